// Round 1
// 1372.437 us; speedup vs baseline: 1.3023x; 1.3023x over previous
//
#include <hip/hip_runtime.h>
#include <math.h>

#define BN_EPS 1e-3f

typedef unsigned short ushort;
typedef unsigned int uint;
typedef __attribute__((ext_vector_type(8))) short bf16x8;
typedef __attribute__((ext_vector_type(4))) float f32x4;

__device__ __forceinline__ float hsig(float x) {
    return fminf(fmaxf(0.2f * x + 0.5f, 0.f), 1.f);
}
__device__ __forceinline__ ushort f2bf(float f) {
    uint u = __float_as_uint(f);
    u += 0x7fffu + ((u >> 16) & 1u);   // RNE
    return (ushort)(u >> 16);
}

// async global->LDS DMA, 16B per lane; LDS dest must be wave-uniform base
// (HW writes at base + lane*16).
__device__ __forceinline__ void gld_lds16(const void* g, void* l) {
    __builtin_amdgcn_global_load_lds(
        (const __attribute__((address_space(1))) void*)g,
        (__attribute__((address_space(3))) void*)l, 16, 0, 0);
}

// ---------------------------------------------------------------------------
// pack_w: fp32 weights [3,Cin,4F]+[3,F,4F] -> bf16 fragment-order, FT=32.
// wp[nblk][step][slot][8], slot = (gate*2+wn)*64 + q*16 + r,
// element = W[k = step*32 + q*8 + j][n = gate*F + nblk*32 + wn*16 + r].
// steps [0,S0) from Wx (k < 3*Cin valid, else 0), rest from Wh.
// grid: (F/32, S), block 256.
// ---------------------------------------------------------------------------
__global__ __launch_bounds__(256)
void pack_w(const float* __restrict__ Wx, int Cin,
            const float* __restrict__ Wh, int F,
            uint4* __restrict__ wp, int S0, int S)
{
    __shared__ ushort Wt[32][136];
    const int nblk = blockIdx.x, step = blockIdx.y;
    const int tid = threadIdx.x;
    const int N4 = 4 * F;

    for (int idx = tid; idx < 32 * 128; idx += 256) {
        int kk = idx >> 7, c = idx & 127;
        int gate = c >> 5, fl = c & 31;
        int n = gate * F + nblk * 32 + fl;
        float v = 0.f;
        if (step < S0) {
            int ka = step * 32 + kk;
            if (ka < 3 * Cin) v = Wx[(long)ka * N4 + n];
        } else {
            int ka = (step - S0) * 32 + kk;
            v = Wh[(long)ka * N4 + n];
        }
        Wt[kk][c] = f2bf(v);
    }
    __syncthreads();

    for (int s = tid; s < 512; s += 256) {
        int colgrp = s >> 6, qq = (s >> 4) & 3, rr = s & 15;
        int gate = colgrp >> 1, wn = colgrp & 1;
        int c = gate * 32 + wn * 16 + rr;
        ushort tmp[8];
#pragma unroll
        for (int j = 0; j < 8; ++j) tmp[j] = Wt[qq * 8 + j][c];
        wp[(long)(nblk * S + step) * 512 + s] = *(const uint4*)tmp;
    }
}

// ---------------------------------------------------------------------------
// Per-layer config for the diagonal-fused gate kernel.
// ---------------------------------------------------------------------------
struct GateCfg {
    const void* a0;        // layer input base at this layer's timestep
    const ushort* h_old;   // bf16 [B,L,F]
    ushort* h_new;
    const uint4* wp;
    const float* bias;
    float* c_state;        // fp32 [B,L,F]
    void* bn_out;          // may be null
    const float* bn_g; const float* bn_b; const float* bn_m; const float* bn_v;
    long a0_bs;            // batch stride (elements) of a0
    long bn_bs;            // batch stride of bn_out
    int C0, S0, S, F;
    int nf_log2;           // log2(F/32)
    int cin1;              // layer-1 fp32-x input path
    int bnf32;             // bn_out is fp32
    int active;
};

// ---------------------------------------------------------------------------
// Diagonal-fused MFMA gate kernel, v2: per-step double-buffered pipeline.
//  - B staged via global_load_lds (lane-linear copy, no VGPR round trip)
//  - A im2col addressing linearized: addr(step) = base + 32*step
//    (since (l<<csh)+ch0 == (base_l<<csh)+kb), 1 bounds check per step
//  - next step's loads issued before current step's MFMAs (T14/T3 2-phase)
// Fixed tile: WM=2, WN=2, MT=2 -> LT=64 rows, FT=32 features (128 cols).
// Block map: [0,512) L3, [512,768) L2, [768,896) L1 (heavy first).
// LDS 24 KB (2 x (4KB A + 8KB B)).
// ---------------------------------------------------------------------------
__global__ __launch_bounds__(256)
void gate_diag(GateCfg c3, GateCfg c2, GateCfg c1, int L)
{
    constexpr int ASLOTS = 256;   // LT*4
    constexpr int BSLOTS = 512;   // 16*FT

    __shared__ __align__(16) ushort As[2][ASLOTS * 8];
    __shared__ __align__(16) ushort Bs[2][BSLOTS * 8];

    GateCfg c; int tile;
    const int bid = blockIdx.x;
    if (bid < 512)      { c = c3; tile = bid; }
    else if (bid < 768) { c = c2; tile = bid - 512; }
    else                { c = c1; tile = bid - 768; }
    if (!c.active) return;

    const int fblk = tile & ((1 << c.nf_log2) - 1);
    const int rest = tile >> c.nf_log2;
    const int lblk = rest & 1;
    const int b = rest >> 1;

    const int tid = threadIdx.x;
    const int lane = tid & 63;
    const int wave = tid >> 6;
    const int wn = wave & 1, wm = wave >> 1;
    const int q = lane >> 4, r = lane & 15;
    const int f0 = fblk * 32;
    const int l0 = lblk * 64;
    const int F = c.F;
    const int c0shift = 31 - __clz(c.C0 > 0 ? c.C0 : 1);
    const int cFshift = 31 - __clz(F);
    const int S = c.S, S0 = c.S0;

    // ---- per-thread A-slot geometry (thread owns slot `tid`) ----
    const int mtile = tid >> 6, within = tid & 63;
    const int qq = within >> 4, rr = within & 15;
    const int row = mtile * 16 + rr;
    const int base_l = l0 + row - 1;

    // linearized im2col base pointers (addr(step) = base + kb, kb = 32*local)
    const ushort* a0p = (const ushort*)c.a0 + (long)b * c.a0_bs
                        + ((long)base_l << c0shift) + qq * 8;
    const ushort* hp  = c.h_old + ((long)b * L + base_l) * F + qq * 8;
    const uint4*  wpB = c.wp + (long)fblk * S * BSLOTS;

    // A fetch for `step` into a register uint4 (zero if out of halo/window)
    auto a_fetch = [&](int step, uint4& out) {
        out = uint4{0u, 0u, 0u, 0u};
        if (c.cin1 && step < S0) {           // L1 step 0: fp32 x input
            if (qq == 0) {
                const float* xb = (const float*)c.a0 + (long)b * c.a0_bs;
                ushort t[8] = {0, 0, 0, 0, 0, 0, 0, 0};
#pragma unroll
                for (int j = 0; j < 3; ++j) {
                    int l = base_l + j;
                    if (l >= 0 && l < L) t[j] = f2bf(xb[l]);
                }
                out = *(const uint4*)t;
            }
            return;
        }
        const ushort* p; int kb, csh;
        if (step < S0) { p = a0p; kb = step * 32;        csh = c0shift; }
        else           { p = hp;  kb = (step - S0) * 32; csh = cFshift; }
        int l = base_l + (kb >> csh);
        if ((unsigned)l < (unsigned)L) out = *(const uint4*)(p + kb);
    };

    // B stage for `step` into Bs[bufi] via async DMA (2 x 16B per thread)
    auto b_stage = [&](int step, int bufi) {
        const uint4* src = wpB + (long)step * BSLOTS + tid;
        ushort* dst = &Bs[bufi][(tid & ~63) * 8];   // wave-uniform base
#pragma unroll
        for (int j = 0; j < 2; ++j)
            gld_lds16(src + j * 256, dst + j * 256 * 8);
    };

    f32x4 acc[2][4];
#pragma unroll
    for (int mt = 0; mt < 2; ++mt)
#pragma unroll
        for (int g = 0; g < 4; ++g) acc[mt][g] = (f32x4)(0.f);

    // ---- prologue: stage step 0 into buffer 0 ----
    {
        uint4 aP;
        b_stage(0, 0);
        a_fetch(0, aP);
        ((uint4*)As[0])[tid] = aP;
    }
    __syncthreads();   // drains vmcnt (DMA) + lgkm (A write)

    // ---- main pipeline: prefetch step+1 while computing step ----
    for (int step = 0; step < S; ++step) {
        const int buf = step & 1;
        const int nbuf = buf ^ 1;
        const bool hasNext = (step + 1 < S);
        uint4 aN;
        if (hasNext) {
            b_stage(step + 1, nbuf);   // async into other buffer
            a_fetch(step + 1, aN);     // global->reg, lands under MFMAs
        }

        bf16x8 af[2], bfr[4];
#pragma unroll
        for (int mt = 0; mt < 2; ++mt)
            af[mt] = *(const bf16x8*)&As[buf][((wm * 2 + mt) * 64 + lane) * 8];
#pragma unroll
        for (int g = 0; g < 4; ++g)
            bfr[g] = *(const bf16x8*)&Bs[buf][((g * 2 + wn) * 64 + lane) * 8];
#pragma unroll
        for (int mt = 0; mt < 2; ++mt)
#pragma unroll
            for (int g = 0; g < 4; ++g)
                acc[mt][g] = __builtin_amdgcn_mfma_f32_16x16x32_bf16(
                    af[mt], bfr[g], acc[mt][g], 0, 0, 0);

        if (hasNext) ((uint4*)As[nbuf])[tid] = aN;
        __syncthreads();   // buffers flip: next step's data ready
    }

    // ---- epilogue: bias, gates, state update, optional BN ----
    const int f = f0 + wn * 16 + r;
    const float b_i = c.bias[f], b_f = c.bias[F + f];
    const float b_c = c.bias[2 * F + f], b_o = c.bias[3 * F + f];
    float sc = 0.f, sh = 0.f;
    if (c.bn_out) {
        sc = c.bn_g[f] * rsqrtf(c.bn_v[f] + BN_EPS);
        sh = c.bn_b[f] - c.bn_m[f] * sc;
    }
#pragma unroll
    for (int mt = 0; mt < 2; ++mt) {
#pragma unroll
        for (int reg = 0; reg < 4; ++reg) {
            const int l = l0 + (wm * 2 + mt) * 16 + q * 4 + reg;
            const long idx = ((long)b * L + l) * F + f;
            float gi = acc[mt][0][reg] + b_i;
            float gf = acc[mt][1][reg] + b_f;
            float gc = acc[mt][2][reg] + b_c;
            float go = acc[mt][3][reg] + b_o;
            float cold = c.c_state[idx];
            float cn = hsig(gf) * cold + hsig(gi) * fmaxf(gc, 0.f);
            float hn = hsig(go) * fmaxf(cn, 0.f);
            c.c_state[idx] = cn;
            c.h_new[idx] = f2bf(hn);
            if (c.bn_out) {
                float bv = hn * sc + sh;
                if (c.bnf32)
                    ((float*)c.bn_out)[(long)b * c.bn_bs + (long)l * F + f] = bv;
                else
                    ((ushort*)c.bn_out)[(long)b * c.bn_bs + (long)l * F + f] = f2bf(bv);
            }
        }
    }
}

// ---------------------------------------------------------------------------
// dense_partial v4: KT=128, N-tile=256, grid (N/256, K/128) = (4,256).
// 4 blocks/CU (16 waves/CU) + explicit depth-2 W prefetch rotation so the
// next rows' loads are in flight under the current rows' 512 FMA cycles.
// ---------------------------------------------------------------------------
#define DP_FMA(kk, W) do {                                         \
    const f32x4 a0 = *(const f32x4*)&A_s[(kk) * 32 + mg * 8];      \
    const f32x4 a1 = *(const f32x4*)&A_s[(kk) * 32 + mg * 8 + 4];  \
    acc[0] += a0.x * (W); acc[1] += a0.y * (W);                    \
    acc[2] += a0.z * (W); acc[3] += a0.w * (W);                    \
    acc[4] += a1.x * (W); acc[5] += a1.y * (W);                    \
    acc[6] += a1.z * (W); acc[7] += a1.w * (W);                    \
} while (0)

__global__ __launch_bounds__(256)
void dense_partial(const float* __restrict__ A,   // [32, K]
                   const float* __restrict__ Wt,  // [K, N]
                   float* __restrict__ partials,  // [nK, 32, N]
                   int K, int N)
{
    __shared__ __align__(16) float A_s[128 * 32];   // 16 KB
    const int n0 = blockIdx.x * 256;
    const int k0 = blockIdx.y * 128;
    const int tid = threadIdx.x;

    for (int idx = tid; idx < 128 * 32; idx += 256) {
        int k = idx >> 5, m = idx & 31;
        A_s[idx] = A[(long)m * K + k0 + k];
    }
    __syncthreads();

    const int nq = (tid & 63) * 4;
    const int mg = tid >> 6;          // m-group: rows mg*8 .. mg*8+7
    f32x4 acc[8];
#pragma unroll
    for (int i = 0; i < 8; ++i) acc[i] = (f32x4)(0.f);

    const float* wptr = &Wt[(long)k0 * N + n0 + nq];
    f32x4 wcur = *(const f32x4*)wptr;
    f32x4 wnx  = *(const f32x4*)(wptr + N);
    wptr += 2 * (long)N;

#pragma unroll 2
    for (int k = 0; k < 126; ++k) {
        f32x4 wnew = *(const f32x4*)wptr;  // k+2, issued before use of wcur
        wptr += N;
        DP_FMA(k, wcur);
        wcur = wnx; wnx = wnew;
    }
    DP_FMA(126, wcur);
    DP_FMA(127, wnx);

#pragma unroll
    for (int mm = 0; mm < 8; ++mm)
        *(f32x4*)&partials[((long)blockIdx.y * 32 + mg * 8 + mm) * N + n0 + nq] = acc[mm];
}

__global__ __launch_bounds__(256)
void dense_reduce_relu(const float* __restrict__ partials,
                       const float* __restrict__ bias,
                       float* __restrict__ out, int N, int nK)
{
    int idx = blockIdx.x * 256 + threadIdx.x;
    int m = idx / N, n = idx % N;
    float s = bias[n];
#pragma unroll 4
    for (int j = 0; j < nK; ++j) s += partials[((long)j * 32 + m) * N + n];
    out[idx] = fmaxf(s, 0.f);
}

// D2: K=1024 fits in LDS once.
__global__ __launch_bounds__(256)
void dense_relu(const float* __restrict__ A, const float* __restrict__ Wt,
                const float* __restrict__ bias, float* __restrict__ out,
                int K, int N)
{
    __shared__ float A_s[1024];
    int n = blockIdx.x * 256 + threadIdx.x;
    int m = blockIdx.y;
    for (int k = threadIdx.x; k < K; k += 256) A_s[k] = A[(long)m * K + k];
    __syncthreads();
    float acc = 0.f;
#pragma unroll 8
    for (int k = 0; k < K; ++k)
        acc += A_s[k] * Wt[(long)k * N + n];
    out[(long)m * N + n] = fmaxf(acc + bias[n], 0.f);
}

__global__ __launch_bounds__(64)
void dense_softmax(const float* __restrict__ A, const float* __restrict__ W,
                   const float* __restrict__ bias, float* __restrict__ out)
{
    int b = blockIdx.x;
    int tid = threadIdx.x;
    __shared__ float logits[5];

    float part[5] = {0.f, 0.f, 0.f, 0.f, 0.f};
    for (int k = tid; k < 512; k += 64) {
        float a = A[b * 512 + k];
#pragma unroll
        for (int j = 0; j < 5; ++j) part[j] += a * W[k * 5 + j];
    }
#pragma unroll
    for (int j = 0; j < 5; ++j) {
        float v = part[j];
        for (int off = 32; off; off >>= 1) v += __shfl_down(v, off);
        if (tid == 0) logits[j] = v + bias[j];
    }
    __syncthreads();
    if (tid == 0) {
        float mx = logits[0];
        for (int j = 1; j < 5; ++j) mx = fmaxf(mx, logits[j]);
        float s = 0.f, e[5];
        for (int j = 0; j < 5; ++j) { e[j] = expf(logits[j] - mx); s += e[j]; }
        for (int j = 0; j < 5; ++j) out[b * 5 + j] = e[j] / s;
    }
}

extern "C" void kernel_launch(void* const* d_in, const int* in_sizes, int n_in,
                              void* d_out, int out_size, void* d_ws, size_t ws_size,
                              hipStream_t stream)
{
    const int B = 32, T = 32, L = 128;
    const int F1 = 64, F2 = 128, F3 = 256;

    const float* x   = (const float*)d_in[0];
    const float* Wx1 = (const float*)d_in[1];
    const float* Wh1 = (const float*)d_in[2];
    const float* b1  = (const float*)d_in[3];
    const float* Wx2 = (const float*)d_in[4];
    const float* Wh2 = (const float*)d_in[5];
    const float* b2  = (const float*)d_in[6];
    const float* Wx3 = (const float*)d_in[7];
    const float* Wh3 = (const float*)d_in[8];
    const float* b3  = (const float*)d_in[9];
    const float* g1  = (const float*)d_in[10];
    const float* be1 = (const float*)d_in[11];
    const float* m1  = (const float*)d_in[12];
    const float* v1  = (const float*)d_in[13];
    const float* g2  = (const float*)d_in[14];
    const float* be2 = (const float*)d_in[15];
    const float* m2  = (const float*)d_in[16];
    const float* v2  = (const float*)d_in[17];
    const float* g3  = (const float*)d_in[18];
    const float* be3 = (const float*)d_in[19];
    const float* m3  = (const float*)d_in[20];
    const float* v3  = (const float*)d_in[21];
    const float* D1  = (const float*)d_in[22];
    const float* db1 = (const float*)d_in[23];
    const float* D2  = (const float*)d_in[24];
    const float* db2 = (const float*)d_in[25];
    const float* D3  = (const float*)d_in[26];
    const float* db3 = (const float*)d_in[27];
    (void)in_sizes; (void)n_in; (void)out_size; (void)ws_size;

    // ---- workspace layout ----
    char* p = (char*)d_ws;
    ushort* h1seq = (ushort*)p; p += (size_t)B * T * L * F1 * 2;       // 16.8 MB
    ushort* h2seq = (ushort*)p; p += (size_t)B * T * L * F2 * 2;       // 33.6 MB
    ushort* h1a = (ushort*)p; p += (size_t)B * L * F1 * 2;
    ushort* h1b = (ushort*)p; p += (size_t)B * L * F1 * 2;
    ushort* h2a = (ushort*)p; p += (size_t)B * L * F2 * 2;
    ushort* h2b = (ushort*)p; p += (size_t)B * L * F2 * 2;
    ushort* h3a = (ushort*)p; p += (size_t)B * L * F3 * 2;
    ushort* h3b = (ushort*)p; p += (size_t)B * L * F3 * 2;
    float*  c1s = (float*)p; p += (size_t)B * L * F1 * 4;
    float*  c2s = (float*)p; p += (size_t)B * L * F2 * 4;
    float*  c3s = (float*)p; p += (size_t)B * L * F3 * 4;
    float*  h3bn = (float*)p; p += (size_t)B * L * F3 * 4;
    uint4*  wp1 = (uint4*)p; p += (size_t)2 * 7 * 512 * 16;
    uint4*  wp2 = (uint4*)p; p += (size_t)4 * 18 * 512 * 16;
    uint4*  wp3 = (uint4*)p; p += (size_t)8 * 36 * 512 * 16;
    float*  a1 = (float*)p; p += (size_t)B * 1024 * 4;
    float*  a2 = (float*)p; p += (size_t)B * 512 * 4;
    // partials: 256*32*1024*4 = 33.55 MB == h2seq slab size, dead by then
    float* partials = (float*)h2seq;

    // ---- pack weights ----
    pack_w<<<dim3(2, 7), 256, 0, stream>>>(Wx1, 1, Wh1, F1, wp1, 1, 7);
    pack_w<<<dim3(4, 18), 256, 0, stream>>>(Wx2, F1, Wh2, F2, wp2, 6, 18);
    pack_w<<<dim3(8, 36), 256, 0, stream>>>(Wx3, F2, Wh3, F3, wp3, 12, 36);

    // ---- zero initial states ----
    hipMemsetAsync(h1a, 0, (size_t)B * L * F1 * 2, stream);
    hipMemsetAsync(h2a, 0, (size_t)B * L * F2 * 2, stream);
    hipMemsetAsync(h3a, 0, (size_t)B * L * F3 * 2, stream);
    hipMemsetAsync(c1s, 0, (size_t)B * L * F1 * 4, stream);
    hipMemsetAsync(c2s, 0, (size_t)B * L * F2 * 4, stream);
    hipMemsetAsync(c3s, 0, (size_t)B * L * F3 * 4, stream);

    // ---- diagonal schedule: dispatch d runs L1@d, L2@d-1, L3@d-2 ----
    for (int d = 0; d < T + 2; ++d) {
        GateCfg c1c = {}, c2c = {}, c3c = {};

        int t1 = d;
        if (t1 >= 0 && t1 < T) {
            c1c.active = 1; c1c.cin1 = 1; c1c.bnf32 = 0;
            c1c.a0 = x + (long)t1 * L; c1c.a0_bs = (long)T * L;
            c1c.C0 = 1; c1c.S0 = 1; c1c.S = 7; c1c.F = F1; c1c.nf_log2 = 1;
            c1c.h_old = (t1 & 1) ? h1b : h1a;
            c1c.h_new = (t1 & 1) ? h1a : h1b;
            c1c.wp = wp1; c1c.bias = b1; c1c.c_state = c1s;
            c1c.bn_out = h1seq + (long)t1 * L * F1; c1c.bn_bs = (long)T * L * F1;
            c1c.bn_g = g1; c1c.bn_b = be1; c1c.bn_m = m1; c1c.bn_v = v1;
        }
        int t2 = d - 1;
        if (t2 >= 0 && t2 < T) {
            c2c.active = 1; c2c.cin1 = 0; c2c.bnf32 = 0;
            c2c.a0 = h1seq + (long)t2 * L * F1; c2c.a0_bs = (long)T * L * F1;
            c2c.C0 = F1; c2c.S0 = 6; c2c.S = 18; c2c.F = F2; c2c.nf_log2 = 2;
            c2c.h_old = (t2 & 1) ? h2b : h2a;
            c2c.h_new = (t2 & 1) ? h2a : h2b;
            c2c.wp = wp2; c2c.bias = b2; c2c.c_state = c2s;
            c2c.bn_out = h2seq + (long)t2 * L * F2; c2c.bn_bs = (long)T * L * F2;
            c2c.bn_g = g2; c2c.bn_b = be2; c2c.bn_m = m2; c2c.bn_v = v2;
        }
        int t3 = d - 2;
        if (t3 >= 0 && t3 < T) {
            c3c.active = 1; c3c.cin1 = 0; c3c.bnf32 = 1;
            c3c.a0 = h2seq + (long)t3 * L * F2; c3c.a0_bs = (long)T * L * F2;
            c3c.C0 = F2; c3c.S0 = 12; c3c.S = 36; c3c.F = F3; c3c.nf_log2 = 3;
            c3c.h_old = (t3 & 1) ? h3b : h3a;
            c3c.h_new = (t3 & 1) ? h3a : h3b;
            c3c.wp = wp3; c3c.bias = b3; c3c.c_state = c3s;
            c3c.bn_out = (t3 == T - 1) ? (void*)h3bn : nullptr;
            c3c.bn_bs = (long)L * F3;
            c3c.bn_g = g3; c3c.bn_b = be3; c3c.bn_m = m3; c3c.bn_v = v3;
        }
        gate_diag<<<896, 256, 0, stream>>>(c3c, c2c, c1c, L);
    }

    // ---- dense head ----
    {
        const int K = L * F3;              // 32768
        dense_partial<<<dim3(4, 256), 256, 0, stream>>>(h3bn, D1, partials, K, 1024);
        dense_reduce_relu<<<(B * 1024) / 256, 256, 0, stream>>>(partials, db1, a1, 1024, 256);
    }
    dense_relu<<<dim3(512 / 256, B), 256, 0, stream>>>(a1, D2, db2, a2, 1024, 512);
    dense_softmax<<<B, 64, 0, stream>>>(a2, D3, db3, (float*)d_out);
}

// Round 2
// 1341.402 us; speedup vs baseline: 1.3324x; 1.0231x over previous
//
#include <hip/hip_runtime.h>
#include <math.h>

#define BN_EPS 1e-3f

typedef unsigned short ushort;
typedef unsigned int uint;
typedef __attribute__((ext_vector_type(8))) short bf16x8;
typedef __attribute__((ext_vector_type(4))) float f32x4;

__device__ __forceinline__ float hsig(float x) {
    return fminf(fmaxf(0.2f * x + 0.5f, 0.f), 1.f);
}
__device__ __forceinline__ ushort f2bf(float f) {
    uint u = __float_as_uint(f);
    u += 0x7fffu + ((u >> 16) & 1u);   // RNE
    return (ushort)(u >> 16);
}

// async global->LDS DMA, 16B per lane; LDS dest is wave-uniform base
// (HW writes at base + lane*16); global src may be per-lane.
__device__ __forceinline__ void gld_lds16(const void* g, void* l) {
    __builtin_amdgcn_global_load_lds(
        (const __attribute__((address_space(1))) void*)g,
        (__attribute__((address_space(3))) void*)l, 16, 0, 0);
}

// ---------------------------------------------------------------------------
// pack_w: fp32 weights [3,Cin,4F]+[3,F,4F] -> bf16 fragment-order, FT=32.
// wp[nblk][step][slot][8], slot = (gate*2+wn)*64 + q*16 + r,
// element = W[k = step*32 + q*8 + j][n = gate*F + nblk*32 + wn*16 + r].
// steps [0,S0) from Wx (k < 3*Cin valid, else 0), rest from Wh.
// grid: (F/32, S), block 256.
// ---------------------------------------------------------------------------
__global__ __launch_bounds__(256)
void pack_w(const float* __restrict__ Wx, int Cin,
            const float* __restrict__ Wh, int F,
            uint4* __restrict__ wp, int S0, int S)
{
    __shared__ ushort Wt[32][136];
    const int nblk = blockIdx.x, step = blockIdx.y;
    const int tid = threadIdx.x;
    const int N4 = 4 * F;

    for (int idx = tid; idx < 32 * 128; idx += 256) {
        int kk = idx >> 7, c = idx & 127;
        int gate = c >> 5, fl = c & 31;
        int n = gate * F + nblk * 32 + fl;
        float v = 0.f;
        if (step < S0) {
            int ka = step * 32 + kk;
            if (ka < 3 * Cin) v = Wx[(long)ka * N4 + n];
        } else {
            int ka = (step - S0) * 32 + kk;
            v = Wh[(long)ka * N4 + n];
        }
        Wt[kk][c] = f2bf(v);
    }
    __syncthreads();

    for (int s = tid; s < 512; s += 256) {
        int colgrp = s >> 6, qq = (s >> 4) & 3, rr = s & 15;
        int gate = colgrp >> 1, wn = colgrp & 1;
        int c = gate * 32 + wn * 16 + rr;
        ushort tmp[8];
#pragma unroll
        for (int j = 0; j < 8; ++j) tmp[j] = Wt[qq * 8 + j][c];
        wp[(long)(nblk * S + step) * 512 + s] = *(const uint4*)tmp;
    }
}

// ---------------------------------------------------------------------------
// Per-layer config for the diagonal-fused gate kernel.
// ---------------------------------------------------------------------------
struct GateCfg {
    const void* a0;        // layer input base at this layer's timestep
    const ushort* h_old;   // bf16 [B,L,F]
    ushort* h_new;
    const uint4* wp;
    const float* bias;
    float* c_state;        // fp32 [B,L,F]
    void* bn_out;          // may be null
    const float* bn_g; const float* bn_b; const float* bn_m; const float* bn_v;
    long a0_bs;            // batch stride (elements) of a0
    long bn_bs;            // batch stride of bn_out
    int C0, S0, S, F;
    int nf_log2;           // log2(F/32)
    int cin1;              // layer-1 fp32-x input path
    int bnf32;             // bn_out is fp32
    int active;
};

// ---------------------------------------------------------------------------
// Diagonal-fused MFMA gate kernel, v3: counted-vmcnt deep pipeline (T3+T4).
//  - ALL staging via global_load_lds (A im2col OOB lanes redirect src to a
//    zero buffer; LDS dest stays lane-linear as HW requires)
//  - triple-buffered LDS, prefetch depth 2: stage(step+2) issued, then
//    s_waitcnt vmcnt(6) -> only stage(step) (issued 2 iters ago) must be
//    done. Loads get ~2 compute phases to cover cross-XCD L2-miss latency.
//  - raw s_barrier + sched_barrier(0) pins; ds_read/MFMA stay C++ so the
//    compiler manages lgkmcnt (no rule-18 hazard).
// Fixed tile: WM=2, WN=2, MT=2 -> LT=64 rows, FT=32 features (128 cols).
// Block map: [0,512) L3, [512,768) L2, [768,896) L1 (heavy first).
// LDS 36 KB (3 x (4KB A + 8KB B)) -> 4 blocks/CU by LDS.
// ---------------------------------------------------------------------------
__global__ __launch_bounds__(256)
void gate_diag(GateCfg c3, GateCfg c2, GateCfg c1, int L,
               const ushort* __restrict__ zbuf)
{
    constexpr int ASLOTS = 256;   // LT*4
    constexpr int BSLOTS = 512;   // 16*FT

    __shared__ __align__(16) ushort As[3][ASLOTS * 8];
    __shared__ __align__(16) ushort Bs[3][BSLOTS * 8];

    GateCfg c; int tile;
    const int bid = blockIdx.x;
    if (bid < 512)      { c = c3; tile = bid; }
    else if (bid < 768) { c = c2; tile = bid - 512; }
    else                { c = c1; tile = bid - 768; }
    if (!c.active) return;

    const int fblk = tile & ((1 << c.nf_log2) - 1);
    const int rest = tile >> c.nf_log2;
    const int lblk = rest & 1;
    const int b = rest >> 1;

    const int tid = threadIdx.x;
    const int lane = tid & 63;
    const int wave = tid >> 6;
    const int wn = wave & 1, wm = wave >> 1;
    const int q = lane >> 4, r = lane & 15;
    const int f0 = fblk * 32;
    const int l0 = lblk * 64;
    const int F = c.F;
    const int c0shift = 31 - __clz(c.C0 > 0 ? c.C0 : 1);
    const int cFshift = 31 - __clz(F);
    const int S = c.S, S0 = c.S0;

    // ---- per-thread A-slot geometry (thread owns slot `tid`) ----
    const int qq = lane >> 4, rr = lane & 15;
    const int row = wave * 16 + rr;
    const int base_l = l0 + row - 1;

    // linearized im2col base pointers (addr(step) = base + kb, kb = 32*local)
    const ushort* a0p = (const ushort*)c.a0 + (long)b * c.a0_bs
                        + ((long)base_l << c0shift) + qq * 8;
    const ushort* hp  = c.h_old + ((long)b * L + base_l) * F + qq * 8;
    const uint4*  wpB = c.wp + (long)fblk * S * BSLOTS;

    // B stage: 2 lane-linear DMA per thread (2 VMEM instrs per wave)
    auto stageB = [&](int step, int bufi) {
        const uint4* src = wpB + (long)step * BSLOTS + tid;
        ushort* dst = &Bs[bufi][(tid & ~63) * 8];   // wave-uniform base
        gld_lds16(src, dst);
        gld_lds16(src + 256, dst + 256 * 8);
    };
    // A stage: 1 DMA per thread; OOB halo lanes read the zero buffer
    auto stageA = [&](int step, int bufi) {
        const ushort* p; int kb, csh;
        if (step < S0) { p = a0p; kb = step * 32;        csh = c0shift; }
        else           { p = hp;  kb = (step - S0) * 32; csh = cFshift; }
        const int l = base_l + (kb >> csh);
        const void* src = ((unsigned)l < (unsigned)L) ? (const void*)(p + kb)
                                                      : (const void*)zbuf;
        gld_lds16(src, &As[bufi][(tid & ~63) * 8]);
    };

    f32x4 acc[2][4];
#pragma unroll
    for (int mt = 0; mt < 2; ++mt)
#pragma unroll
        for (int g = 0; g < 4; ++g) acc[mt][g] = (f32x4)(0.f);

    // ---- prologue: stage steps 0,1 into buffers 0,1 ----
    if (c.cin1) {
        // L1 step 0 (fp32 x input, per-element halo): reg path + ds_write.
        // Keeping this out of the loop keeps the vmcnt arithmetic uniform.
        uint4 a0v = {0u, 0u, 0u, 0u};
        if (qq == 0) {
            const float* xb = (const float*)c.a0 + (long)b * c.a0_bs;
            ushort t[8] = {0, 0, 0, 0, 0, 0, 0, 0};
#pragma unroll
            for (int j = 0; j < 3; ++j) {
                int l = base_l + j;
                if (l >= 0 && l < L) t[j] = f2bf(xb[l]);
            }
            a0v = *(const uint4*)t;
        }
        ((uint4*)As[0])[tid] = a0v;
        asm volatile("s_waitcnt lgkmcnt(0)" ::: "memory");
        stageB(0, 0);
    } else {
        stageB(0, 0);
        stageA(0, 0);
    }
    stageB(1, 1);
    stageA(1, 1);

    // ---- main pipeline: 3 VMEM instrs per stage, depth-2 counted waits ----
    for (int step = 0; step < S; ++step) {
        const int buf = step % 3;
        if (step + 2 < S) {
            const int nb = (step + 2) % 3;
            stageB(step + 2, nb);
            stageA(step + 2, nb);
            asm volatile("s_waitcnt vmcnt(6)" ::: "memory");
        } else if (step + 1 < S) {
            asm volatile("s_waitcnt vmcnt(3)" ::: "memory");
        } else {
            asm volatile("s_waitcnt vmcnt(0)" ::: "memory");
        }
        __builtin_amdgcn_s_barrier();          // buf[step%3] ready for all waves
        __builtin_amdgcn_sched_barrier(0);

        bf16x8 af[2], bfr[4];
#pragma unroll
        for (int mt = 0; mt < 2; ++mt)
            af[mt] = *(const bf16x8*)&As[buf][((wm * 2 + mt) * 64 + lane) * 8];
#pragma unroll
        for (int g = 0; g < 4; ++g)
            bfr[g] = *(const bf16x8*)&Bs[buf][((g * 2 + wn) * 64 + lane) * 8];
#pragma unroll
        for (int mt = 0; mt < 2; ++mt)
#pragma unroll
            for (int g = 0; g < 4; ++g)
                acc[mt][g] = __builtin_amdgcn_mfma_f32_16x16x32_bf16(
                    af[mt], bfr[g], acc[mt][g], 0, 0, 0);

        __builtin_amdgcn_sched_barrier(0);
        __builtin_amdgcn_s_barrier();          // reads done: buf reusable
    }

    // ---- epilogue: bias, gates, state update, optional BN ----
    const int f = f0 + wn * 16 + r;
    const float b_i = c.bias[f], b_f = c.bias[F + f];
    const float b_c = c.bias[2 * F + f], b_o = c.bias[3 * F + f];
    float sc = 0.f, sh = 0.f;
    if (c.bn_out) {
        sc = c.bn_g[f] * rsqrtf(c.bn_v[f] + BN_EPS);
        sh = c.bn_b[f] - c.bn_m[f] * sc;
    }
#pragma unroll
    for (int mt = 0; mt < 2; ++mt) {
#pragma unroll
        for (int reg = 0; reg < 4; ++reg) {
            const int l = l0 + (wm * 2 + mt) * 16 + q * 4 + reg;
            const long idx = ((long)b * L + l) * F + f;
            float gi = acc[mt][0][reg] + b_i;
            float gf = acc[mt][1][reg] + b_f;
            float gc = acc[mt][2][reg] + b_c;
            float go = acc[mt][3][reg] + b_o;
            float cold = c.c_state[idx];
            float cn = hsig(gf) * cold + hsig(gi) * fmaxf(gc, 0.f);
            float hn = hsig(go) * fmaxf(cn, 0.f);
            c.c_state[idx] = cn;
            c.h_new[idx] = f2bf(hn);
            if (c.bn_out) {
                float bv = hn * sc + sh;
                if (c.bnf32)
                    ((float*)c.bn_out)[(long)b * c.bn_bs + (long)l * F + f] = bv;
                else
                    ((ushort*)c.bn_out)[(long)b * c.bn_bs + (long)l * F + f] = f2bf(bv);
            }
        }
    }
}

// ---------------------------------------------------------------------------
// dense_partial v4: KT=128, N-tile=256, grid (N/256, K/128) = (4,256).
// 4 blocks/CU (16 waves/CU) + explicit depth-2 W prefetch rotation so the
// next rows' loads are in flight under the current rows' 512 FMA cycles.
// ---------------------------------------------------------------------------
#define DP_FMA(kk, W) do {                                         \
    const f32x4 a0 = *(const f32x4*)&A_s[(kk) * 32 + mg * 8];      \
    const f32x4 a1 = *(const f32x4*)&A_s[(kk) * 32 + mg * 8 + 4];  \
    acc[0] += a0.x * (W); acc[1] += a0.y * (W);                    \
    acc[2] += a0.z * (W); acc[3] += a0.w * (W);                    \
    acc[4] += a1.x * (W); acc[5] += a1.y * (W);                    \
    acc[6] += a1.z * (W); acc[7] += a1.w * (W);                    \
} while (0)

__global__ __launch_bounds__(256)
void dense_partial(const float* __restrict__ A,   // [32, K]
                   const float* __restrict__ Wt,  // [K, N]
                   float* __restrict__ partials,  // [nK, 32, N]
                   int K, int N)
{
    __shared__ __align__(16) float A_s[128 * 32];   // 16 KB
    const int n0 = blockIdx.x * 256;
    const int k0 = blockIdx.y * 128;
    const int tid = threadIdx.x;

    for (int idx = tid; idx < 128 * 32; idx += 256) {
        int k = idx >> 5, m = idx & 31;
        A_s[idx] = A[(long)m * K + k0 + k];
    }
    __syncthreads();

    const int nq = (tid & 63) * 4;
    const int mg = tid >> 6;          // m-group: rows mg*8 .. mg*8+7
    f32x4 acc[8];
#pragma unroll
    for (int i = 0; i < 8; ++i) acc[i] = (f32x4)(0.f);

    const float* wptr = &Wt[(long)k0 * N + n0 + nq];
    f32x4 wcur = *(const f32x4*)wptr;
    f32x4 wnx  = *(const f32x4*)(wptr + N);
    wptr += 2 * (long)N;

#pragma unroll 2
    for (int k = 0; k < 126; ++k) {
        f32x4 wnew = *(const f32x4*)wptr;  // k+2, issued before use of wcur
        wptr += N;
        DP_FMA(k, wcur);
        wcur = wnx; wnx = wnew;
    }
    DP_FMA(126, wcur);
    DP_FMA(127, wnx);

#pragma unroll
    for (int mm = 0; mm < 8; ++mm)
        *(f32x4*)&partials[((long)blockIdx.y * 32 + mg * 8 + mm) * N + n0 + nq] = acc[mm];
}

__global__ __launch_bounds__(256)
void dense_reduce_relu(const float* __restrict__ partials,
                       const float* __restrict__ bias,
                       float* __restrict__ out, int N, int nK)
{
    int idx = blockIdx.x * 256 + threadIdx.x;
    int m = idx / N, n = idx % N;
    float s = bias[n];
#pragma unroll 4
    for (int j = 0; j < nK; ++j) s += partials[((long)j * 32 + m) * N + n];
    out[idx] = fmaxf(s, 0.f);
}

// D2: K=1024 fits in LDS once.
__global__ __launch_bounds__(256)
void dense_relu(const float* __restrict__ A, const float* __restrict__ Wt,
                const float* __restrict__ bias, float* __restrict__ out,
                int K, int N)
{
    __shared__ float A_s[1024];
    int n = blockIdx.x * 256 + threadIdx.x;
    int m = blockIdx.y;
    for (int k = threadIdx.x; k < K; k += 256) A_s[k] = A[(long)m * K + k];
    __syncthreads();
    float acc = 0.f;
#pragma unroll 8
    for (int k = 0; k < K; ++k)
        acc += A_s[k] * Wt[(long)k * N + n];
    out[(long)m * N + n] = fmaxf(acc + bias[n], 0.f);
}

__global__ __launch_bounds__(64)
void dense_softmax(const float* __restrict__ A, const float* __restrict__ W,
                   const float* __restrict__ bias, float* __restrict__ out)
{
    int b = blockIdx.x;
    int tid = threadIdx.x;
    __shared__ float logits[5];

    float part[5] = {0.f, 0.f, 0.f, 0.f, 0.f};
    for (int k = tid; k < 512; k += 64) {
        float a = A[b * 512 + k];
#pragma unroll
        for (int j = 0; j < 5; ++j) part[j] += a * W[k * 5 + j];
    }
#pragma unroll
    for (int j = 0; j < 5; ++j) {
        float v = part[j];
        for (int off = 32; off; off >>= 1) v += __shfl_down(v, off);
        if (tid == 0) logits[j] = v + bias[j];
    }
    __syncthreads();
    if (tid == 0) {
        float mx = logits[0];
        for (int j = 1; j < 5; ++j) mx = fmaxf(mx, logits[j]);
        float s = 0.f, e[5];
        for (int j = 0; j < 5; ++j) { e[j] = expf(logits[j] - mx); s += e[j]; }
        for (int j = 0; j < 5; ++j) out[b * 5 + j] = e[j] / s;
    }
}

extern "C" void kernel_launch(void* const* d_in, const int* in_sizes, int n_in,
                              void* d_out, int out_size, void* d_ws, size_t ws_size,
                              hipStream_t stream)
{
    const int B = 32, T = 32, L = 128;
    const int F1 = 64, F2 = 128, F3 = 256;

    const float* x   = (const float*)d_in[0];
    const float* Wx1 = (const float*)d_in[1];
    const float* Wh1 = (const float*)d_in[2];
    const float* b1  = (const float*)d_in[3];
    const float* Wx2 = (const float*)d_in[4];
    const float* Wh2 = (const float*)d_in[5];
    const float* b2  = (const float*)d_in[6];
    const float* Wx3 = (const float*)d_in[7];
    const float* Wh3 = (const float*)d_in[8];
    const float* b3  = (const float*)d_in[9];
    const float* g1  = (const float*)d_in[10];
    const float* be1 = (const float*)d_in[11];
    const float* m1  = (const float*)d_in[12];
    const float* v1  = (const float*)d_in[13];
    const float* g2  = (const float*)d_in[14];
    const float* be2 = (const float*)d_in[15];
    const float* m2  = (const float*)d_in[16];
    const float* v2  = (const float*)d_in[17];
    const float* g3  = (const float*)d_in[18];
    const float* be3 = (const float*)d_in[19];
    const float* m3  = (const float*)d_in[20];
    const float* v3  = (const float*)d_in[21];
    const float* D1  = (const float*)d_in[22];
    const float* db1 = (const float*)d_in[23];
    const float* D2  = (const float*)d_in[24];
    const float* db2 = (const float*)d_in[25];
    const float* D3  = (const float*)d_in[26];
    const float* db3 = (const float*)d_in[27];
    (void)in_sizes; (void)n_in; (void)out_size; (void)ws_size;

    // ---- workspace layout ----
    char* p = (char*)d_ws;
    ushort* h1seq = (ushort*)p; p += (size_t)B * T * L * F1 * 2;       // 16.8 MB
    ushort* h2seq = (ushort*)p; p += (size_t)B * T * L * F2 * 2;       // 33.6 MB
    ushort* h1a = (ushort*)p; p += (size_t)B * L * F1 * 2;
    ushort* h1b = (ushort*)p; p += (size_t)B * L * F1 * 2;
    ushort* h2a = (ushort*)p; p += (size_t)B * L * F2 * 2;
    ushort* h2b = (ushort*)p; p += (size_t)B * L * F2 * 2;
    ushort* h3a = (ushort*)p; p += (size_t)B * L * F3 * 2;
    ushort* h3b = (ushort*)p; p += (size_t)B * L * F3 * 2;
    float*  c1s = (float*)p; p += (size_t)B * L * F1 * 4;
    float*  c2s = (float*)p; p += (size_t)B * L * F2 * 4;
    float*  c3s = (float*)p; p += (size_t)B * L * F3 * 4;
    float*  h3bn = (float*)p; p += (size_t)B * L * F3 * 4;
    uint4*  wp1 = (uint4*)p; p += (size_t)2 * 7 * 512 * 16;
    uint4*  wp2 = (uint4*)p; p += (size_t)4 * 18 * 512 * 16;
    uint4*  wp3 = (uint4*)p; p += (size_t)8 * 36 * 512 * 16;
    float*  a1 = (float*)p; p += (size_t)B * 1024 * 4;
    float*  a2 = (float*)p; p += (size_t)B * 512 * 4;
    ushort* zbuf = (ushort*)p; p += 64;          // zero src for OOB DMA lanes
    // partials: 256*32*1024*4 = 33.55 MB == h2seq slab size, dead by then
    float* partials = (float*)h2seq;

    // ---- pack weights ----
    pack_w<<<dim3(2, 7), 256, 0, stream>>>(Wx1, 1, Wh1, F1, wp1, 1, 7);
    pack_w<<<dim3(4, 18), 256, 0, stream>>>(Wx2, F1, Wh2, F2, wp2, 6, 18);
    pack_w<<<dim3(8, 36), 256, 0, stream>>>(Wx3, F2, Wh3, F3, wp3, 12, 36);

    // ---- zero initial states ----
    hipMemsetAsync(h1a, 0, (size_t)B * L * F1 * 2, stream);
    hipMemsetAsync(h2a, 0, (size_t)B * L * F2 * 2, stream);
    hipMemsetAsync(h3a, 0, (size_t)B * L * F3 * 2, stream);
    hipMemsetAsync(c1s, 0, (size_t)B * L * F1 * 4, stream);
    hipMemsetAsync(c2s, 0, (size_t)B * L * F2 * 4, stream);
    hipMemsetAsync(c3s, 0, (size_t)B * L * F3 * 4, stream);
    hipMemsetAsync(zbuf, 0, 64, stream);

    // ---- diagonal schedule: dispatch d runs L1@d, L2@d-1, L3@d-2 ----
    for (int d = 0; d < T + 2; ++d) {
        GateCfg c1c = {}, c2c = {}, c3c = {};

        int t1 = d;
        if (t1 >= 0 && t1 < T) {
            c1c.active = 1; c1c.cin1 = 1; c1c.bnf32 = 0;
            c1c.a0 = x + (long)t1 * L; c1c.a0_bs = (long)T * L;
            c1c.C0 = 1; c1c.S0 = 1; c1c.S = 7; c1c.F = F1; c1c.nf_log2 = 1;
            c1c.h_old = (t1 & 1) ? h1b : h1a;
            c1c.h_new = (t1 & 1) ? h1a : h1b;
            c1c.wp = wp1; c1c.bias = b1; c1c.c_state = c1s;
            c1c.bn_out = h1seq + (long)t1 * L * F1; c1c.bn_bs = (long)T * L * F1;
            c1c.bn_g = g1; c1c.bn_b = be1; c1c.bn_m = m1; c1c.bn_v = v1;
        }
        int t2 = d - 1;
        if (t2 >= 0 && t2 < T) {
            c2c.active = 1; c2c.cin1 = 0; c2c.bnf32 = 0;
            c2c.a0 = h1seq + (long)t2 * L * F1; c2c.a0_bs = (long)T * L * F1;
            c2c.C0 = F1; c2c.S0 = 6; c2c.S = 18; c2c.F = F2; c2c.nf_log2 = 2;
            c2c.h_old = (t2 & 1) ? h2b : h2a;
            c2c.h_new = (t2 & 1) ? h2a : h2b;
            c2c.wp = wp2; c2c.bias = b2; c2c.c_state = c2s;
            c2c.bn_out = h2seq + (long)t2 * L * F2; c2c.bn_bs = (long)T * L * F2;
            c2c.bn_g = g2; c2c.bn_b = be2; c2c.bn_m = m2; c2c.bn_v = v2;
        }
        int t3 = d - 2;
        if (t3 >= 0 && t3 < T) {
            c3c.active = 1; c3c.cin1 = 0; c3c.bnf32 = 1;
            c3c.a0 = h2seq + (long)t3 * L * F2; c3c.a0_bs = (long)T * L * F2;
            c3c.C0 = F2; c3c.S0 = 12; c3c.S = 36; c3c.F = F3; c3c.nf_log2 = 3;
            c3c.h_old = (t3 & 1) ? h3b : h3a;
            c3c.h_new = (t3 & 1) ? h3a : h3b;
            c3c.wp = wp3; c3c.bias = b3; c3c.c_state = c3s;
            c3c.bn_out = (t3 == T - 1) ? (void*)h3bn : nullptr;
            c3c.bn_bs = (long)L * F3;
            c3c.bn_g = g3; c3c.bn_b = be3; c3c.bn_m = m3; c3c.bn_v = v3;
        }
        gate_diag<<<896, 256, 0, stream>>>(c3c, c2c, c1c, L, zbuf);
    }

    // ---- dense head ----
    {
        const int K = L * F3;              // 32768
        dense_partial<<<dim3(4, 256), 256, 0, stream>>>(h3bn, D1, partials, K, 1024);
        dense_reduce_relu<<<(B * 1024) / 256, 256, 0, stream>>>(partials, db1, a1, 1024, 256);
    }
    dense_relu<<<dim3(512 / 256, B), 256, 0, stream>>>(a1, D2, db2, a2, 1024, 512);
    dense_softmax<<<B, 64, 0, stream>>>(a2, D3, db3, (float*)d_out);
}

// Round 3
// 1333.060 us; speedup vs baseline: 1.3408x; 1.0063x over previous
//
#include <hip/hip_runtime.h>
#include <math.h>

#define BN_EPS 1e-3f

typedef unsigned short ushort;
typedef unsigned int uint;
typedef __attribute__((ext_vector_type(8))) short bf16x8;
typedef __attribute__((ext_vector_type(4))) float f32x4;

__device__ __forceinline__ float hsig(float x) {
    return fminf(fmaxf(0.2f * x + 0.5f, 0.f), 1.f);
}
__device__ __forceinline__ ushort f2bf(float f) {
    uint u = __float_as_uint(f);
    u += 0x7fffu + ((u >> 16) & 1u);   // RNE
    return (ushort)(u >> 16);
}

// ---------------------------------------------------------------------------
// pack_w: fp32 weights [3,Cin,4F]+[3,F,4F] -> bf16 fragment-order, FT=32.
// wp[nblk][step][slot][8], slot = (gate*2+wn)*64 + q*16 + r,
// element = W[k = step*32 + q*8 + j][n = gate*F + nblk*32 + wn*16 + r].
// steps [0,S0) from Wx (k < 3*Cin valid, else 0), rest from Wh.
// grid: (F/32, S), block 256.
// ---------------------------------------------------------------------------
__global__ __launch_bounds__(256)
void pack_w(const float* __restrict__ Wx, int Cin,
            const float* __restrict__ Wh, int F,
            uint4* __restrict__ wp, int S0, int S)
{
    __shared__ ushort Wt[32][136];
    const int nblk = blockIdx.x, step = blockIdx.y;
    const int tid = threadIdx.x;
    const int N4 = 4 * F;

    for (int idx = tid; idx < 32 * 128; idx += 256) {
        int kk = idx >> 7, c = idx & 127;
        int gate = c >> 5, fl = c & 31;
        int n = gate * F + nblk * 32 + fl;
        float v = 0.f;
        if (step < S0) {
            int ka = step * 32 + kk;
            if (ka < 3 * Cin) v = Wx[(long)ka * N4 + n];
        } else {
            int ka = (step - S0) * 32 + kk;
            v = Wh[(long)ka * N4 + n];
        }
        Wt[kk][c] = f2bf(v);
    }
    __syncthreads();

    for (int s = tid; s < 512; s += 256) {
        int colgrp = s >> 6, qq = (s >> 4) & 3, rr = s & 15;
        int gate = colgrp >> 1, wn = colgrp & 1;
        int c = gate * 32 + wn * 16 + rr;
        ushort tmp[8];
#pragma unroll
        for (int j = 0; j < 8; ++j) tmp[j] = Wt[qq * 8 + j][c];
        wp[(long)(nblk * S + step) * 512 + s] = *(const uint4*)tmp;
    }
}

// ---------------------------------------------------------------------------
// Per-layer config for the diagonal-fused gate kernel.
// ---------------------------------------------------------------------------
struct GateCfg {
    const void* a0;        // layer input base at this layer's timestep
    const ushort* h_old;   // bf16 [B,L,F]
    ushort* h_new;
    const uint4* wp;
    const float* bias;
    float* c_state;        // fp32 [B,L,F]
    void* bn_out;          // may be null
    const float* bn_g; const float* bn_b; const float* bn_m; const float* bn_v;
    long a0_bs;            // batch stride (elements) of a0
    long bn_bs;            // batch stride of bn_out
    int C0A, S0, S, F;     // C0A = a0 channels in slab (L1: 32 im2col)
    int nf_log2;           // log2(F/32)
    int cin1;              // layer-1 fp32-x input path
    int bnf32;             // bn_out is fp32
    int active;
};

// ---------------------------------------------------------------------------
// Diagonal-fused MFMA gate kernel, v4: LDS-resident A slab, reg-resident B.
//  - the block's ENTIRE A working set (rows l0-1..l0+64, a0+h channels,
//    50.7/26/13 KB for L3/L2/L1) is staged ONCE at the prologue into an
//    XOR-swizzled slab (byte ^= (ri&7)<<4 -> stride-768 row reads are
//    bank-conflict-free). The K-loop does no global A traffic at all.
//  - B fragments load straight global->VGPR (L2-warm, shared by all
//    same-XCD blocks) with a static 2-deep double-buffer (bA/bB).
//  - NO barriers / waitcnt in the main loop: LDS is read-only after the
//    single prologue barrier; latency hidden by 12 waves/CU (3 blocks).
//  - L1 step-0 (fp32 x, 3 taps): 4 KB im2col mini-region in the slab;
//    k>=3 slots are zero (and their packed weights are zero anyway).
// Fixed tile: WM=2, WN=2, MT=2 -> LT=64 rows, FT=32 features (128 cols).
// Block map: [0,512) L3, [512,768) L2, [768,896) L1 (heavy first).
// ---------------------------------------------------------------------------
#define MAX_SLAB (66 * 768)   // 50688 B (L3: 66 rows x 384 ch x 2 B)

__global__ __launch_bounds__(256)
void gate_diag(GateCfg c3, GateCfg c2, GateCfg c1, int L)
{
    __shared__ __align__(16) char slab[MAX_SLAB];

    GateCfg c; int tile;
    const int bid = blockIdx.x;
    if (bid < 512)      { c = c3; tile = bid; }
    else if (bid < 768) { c = c2; tile = bid - 512; }
    else                { c = c1; tile = bid - 768; }
    if (!c.active) return;

    const int fblk = tile & ((1 << c.nf_log2) - 1);
    const int rest = tile >> c.nf_log2;
    const int lblk = rest & 1;
    const int b = rest >> 1;

    const int tid = threadIdx.x;
    const int lane = tid & 63;
    const int wave = tid >> 6;
    const int wn = wave & 1, wm = wave >> 1;
    const int q = lane >> 4, r = lane & 15;
    const int f0 = fblk * 32;
    const int l0 = lblk * 64;
    const int F = c.F;
    const int C0A = c.C0A;
    const int S = c.S, S0 = c.S0;
    const int c0shift = 31 - __clz(C0A);
    const int cFshift = 31 - __clz(F);
    const int RS = (C0A + F) * 2;       // bytes per slab row
    const int NCH = RS >> 4;            // 16B chunks per row

    // ---- B: direct global->reg fragment loads, double-buffered ----
    const uint4* wpB = c.wp + (long)fblk * S * 512 + wn * 64 + lane;
    bf16x8 bA[4], bB[4];
    auto loadB = [&](int step, bf16x8* bv) {
#pragma unroll
        for (int g = 0; g < 4; ++g)
            bv[g] = *(const bf16x8*)(wpB + (long)step * 512 + g * 128);
    };
    loadB(0, bA);   // in flight under the slab staging

    // ---- stage A slab (once) ----
    if (c.cin1) {
        // im2col of fp32 x into ch [0,32): slab[ri][k] = x[l0+ri-1+k], k<3
        const float* xb = (const float*)c.a0 + (long)b * c.a0_bs;
        for (int s = tid; s < 66 * 4; s += 256) {
            int ri = s >> 2, co = s & 3;
            uint4 v = {0u, 0u, 0u, 0u};
            if (co == 0) {
                ushort t[8] = {0, 0, 0, 0, 0, 0, 0, 0};
#pragma unroll
                for (int j = 0; j < 3; ++j) {
                    int l = l0 - 1 + ri + j;
                    if (l >= 0 && l < L) t[j] = f2bf(xb[l]);
                }
                v = *(const uint4*)t;
            }
            int ba = (ri * RS + co * 16) ^ ((ri & 7) << 4);
            *(uint4*)(slab + ba) = v;
        }
    }
    {
        const ushort* a0b = (const ushort*)c.a0 + (long)b * c.a0_bs;
        const ushort* hb  = c.h_old + (long)b * L * F;
        const int c0bytes = C0A * 2;
        for (int s = tid; s < 66 * NCH; s += 256) {
            int ri = s / NCH, co = s - ri * NCH;
            int boff = co * 16;
            if (c.cin1 && boff < c0bytes) continue;   // im2col region
            int l = l0 - 1 + ri;
            uint4 v = {0u, 0u, 0u, 0u};
            if ((unsigned)l < (unsigned)L) {
                if (boff >= c0bytes)
                    v = *(const uint4*)(hb + (long)l * F + ((boff - c0bytes) >> 1));
                else
                    v = *(const uint4*)(a0b + (long)l * C0A + (boff >> 1));
            }
            int ba = (ri * RS + boff) ^ ((ri & 7) << 4);
            *(uint4*)(slab + ba) = v;
        }
    }
    __syncthreads();   // the ONLY barrier: slab is read-only from here on

    // ---- main loop: ds_read A fragments + MFMA, no sync ----
    f32x4 acc[2][4];
#pragma unroll
    for (int mt = 0; mt < 2; ++mt)
#pragma unroll
        for (int g = 0; g < 4; ++g) acc[mt][g] = (f32x4)(0.f);

    const int laneoff0 = q * 16;   // q*8 channels * 2 B

    auto compute = [&](int step, bf16x8* bv) {
        int kb, csh, cbyte;
        if (step < S0) { kb = step * 32;        csh = c0shift; cbyte = 0; }
        else           { kb = (step - S0) * 32; csh = cFshift; cbyte = C0A * 2; }
        const int tap = kb >> csh;
        const int choff = cbyte + ((kb & ((1 << csh) - 1)) << 1) + laneoff0;
        bf16x8 af[2];
#pragma unroll
        for (int mt = 0; mt < 2; ++mt) {
            int ri = (wm * 2 + mt) * 16 + r + tap;
            int ba = (ri * RS + choff) ^ ((ri & 7) << 4);
            af[mt] = *(const bf16x8*)(slab + ba);
        }
#pragma unroll
        for (int mt = 0; mt < 2; ++mt)
#pragma unroll
            for (int g = 0; g < 4; ++g)
                acc[mt][g] = __builtin_amdgcn_mfma_f32_16x16x32_bf16(
                    af[mt], bv[g], acc[mt][g], 0, 0, 0);
    };

    int step = 0;
    for (; step + 2 <= S; step += 2) {
        loadB(step + 1, bB);
        compute(step, bA);
        if (step + 2 < S) loadB(step + 2, bA);
        compute(step + 1, bB);
    }
    if (step < S) compute(step, bA);   // odd-S tail (L1: S=7)

    // ---- epilogue: bias, gates, state update, optional BN ----
    const int f = f0 + wn * 16 + r;
    const float b_i = c.bias[f], b_f = c.bias[F + f];
    const float b_c = c.bias[2 * F + f], b_o = c.bias[3 * F + f];
    float sc = 0.f, sh = 0.f;
    if (c.bn_out) {
        sc = c.bn_g[f] * rsqrtf(c.bn_v[f] + BN_EPS);
        sh = c.bn_b[f] - c.bn_m[f] * sc;
    }
#pragma unroll
    for (int mt = 0; mt < 2; ++mt) {
#pragma unroll
        for (int reg = 0; reg < 4; ++reg) {
            const int l = l0 + (wm * 2 + mt) * 16 + q * 4 + reg;
            const long idx = ((long)b * L + l) * F + f;
            float gi = acc[mt][0][reg] + b_i;
            float gf = acc[mt][1][reg] + b_f;
            float gc = acc[mt][2][reg] + b_c;
            float go = acc[mt][3][reg] + b_o;
            float cold = c.c_state[idx];
            float cn = hsig(gf) * cold + hsig(gi) * fmaxf(gc, 0.f);
            float hn = hsig(go) * fmaxf(cn, 0.f);
            c.c_state[idx] = cn;
            c.h_new[idx] = f2bf(hn);
            if (c.bn_out) {
                float bv = hn * sc + sh;
                if (c.bnf32)
                    ((float*)c.bn_out)[(long)b * c.bn_bs + (long)l * F + f] = bv;
                else
                    ((ushort*)c.bn_out)[(long)b * c.bn_bs + (long)l * F + f] = f2bf(bv);
            }
        }
    }
}

// ---------------------------------------------------------------------------
// dense_partial v5: KT=128, N-tile=256, grid (4, 256) = 4 blocks/CU.
// Coalesced A staging into pad-33 LDS (write 2-way-free, read broadcast);
// static 4-deep W-row rotation keeps 4 loads in flight per thread.
// ---------------------------------------------------------------------------
#define DP_FMA(kk, W) do {                                         \
    const float* ap = &A_s[(kk) * 33 + mg * 8];                    \
    acc[0] += ap[0] * (W); acc[1] += ap[1] * (W);                  \
    acc[2] += ap[2] * (W); acc[3] += ap[3] * (W);                  \
    acc[4] += ap[4] * (W); acc[5] += ap[5] * (W);                  \
    acc[6] += ap[6] * (W); acc[7] += ap[7] * (W);                  \
} while (0)

__global__ __launch_bounds__(256)
void dense_partial(const float* __restrict__ A,   // [32, K]
                   const float* __restrict__ Wt,  // [K, N]
                   float* __restrict__ partials,  // [nK, 32, N]
                   int K, int N)
{
    __shared__ __align__(16) float A_s[128 * 33];   // 16.9 KB, pad 33
    const int n0 = blockIdx.x * 256;
    const int k0 = blockIdx.y * 128;
    const int tid = threadIdx.x;

    for (int idx = tid; idx < 128 * 32; idx += 256) {
        int m = idx >> 7, kk = idx & 127;            // coalesced along k
        A_s[kk * 33 + m] = A[(long)m * K + k0 + kk];
    }
    __syncthreads();

    const int nq = (tid & 63) * 4;
    const int mg = tid >> 6;          // m-group: rows mg*8 .. mg*8+7
    f32x4 acc[8];
#pragma unroll
    for (int i = 0; i < 8; ++i) acc[i] = (f32x4)(0.f);

    const float* wp0 = &Wt[(long)k0 * N + n0 + nq];
#define LDW(kk) (*(const f32x4*)(wp0 + (long)(kk) * N))
    f32x4 wa = LDW(0), wb = LDW(1), wc = LDW(2), wd = LDW(3);

    for (int k = 0; k < 124; k += 4) {
        DP_FMA(k + 0, wa); wa = LDW(k + 4);
        DP_FMA(k + 1, wb); wb = LDW(k + 5);
        DP_FMA(k + 2, wc); wc = LDW(k + 6);
        DP_FMA(k + 3, wd); wd = LDW(k + 7);
    }
    DP_FMA(124, wa); DP_FMA(125, wb); DP_FMA(126, wc); DP_FMA(127, wd);
#undef LDW

#pragma unroll
    for (int mm = 0; mm < 8; ++mm)
        *(f32x4*)&partials[((long)blockIdx.y * 32 + mg * 8 + mm) * N + n0 + nq] = acc[mm];
}

__global__ __launch_bounds__(256)
void dense_reduce_relu(const float* __restrict__ partials,
                       const float* __restrict__ bias,
                       float* __restrict__ out, int N, int nK)
{
    int idx = blockIdx.x * 256 + threadIdx.x;
    int m = idx / N, n = idx % N;
    float s = bias[n];
#pragma unroll 4
    for (int j = 0; j < nK; ++j) s += partials[((long)j * 32 + m) * N + n];
    out[idx] = fmaxf(s, 0.f);
}

// D2: K=1024 fits in LDS once.
__global__ __launch_bounds__(256)
void dense_relu(const float* __restrict__ A, const float* __restrict__ Wt,
                const float* __restrict__ bias, float* __restrict__ out,
                int K, int N)
{
    __shared__ float A_s[1024];
    int n = blockIdx.x * 256 + threadIdx.x;
    int m = blockIdx.y;
    for (int k = threadIdx.x; k < K; k += 256) A_s[k] = A[(long)m * K + k];
    __syncthreads();
    float acc = 0.f;
#pragma unroll 8
    for (int k = 0; k < K; ++k)
        acc += A_s[k] * Wt[(long)k * N + n];
    out[(long)m * N + n] = fmaxf(acc + bias[n], 0.f);
}

__global__ __launch_bounds__(64)
void dense_softmax(const float* __restrict__ A, const float* __restrict__ W,
                   const float* __restrict__ bias, float* __restrict__ out)
{
    int b = blockIdx.x;
    int tid = threadIdx.x;
    __shared__ float logits[5];

    float part[5] = {0.f, 0.f, 0.f, 0.f, 0.f};
    for (int k = tid; k < 512; k += 64) {
        float a = A[b * 512 + k];
#pragma unroll
        for (int j = 0; j < 5; ++j) part[j] += a * W[k * 5 + j];
    }
#pragma unroll
    for (int j = 0; j < 5; ++j) {
        float v = part[j];
        for (int off = 32; off; off >>= 1) v += __shfl_down(v, off);
        if (tid == 0) logits[j] = v + bias[j];
    }
    __syncthreads();
    if (tid == 0) {
        float mx = logits[0];
        for (int j = 1; j < 5; ++j) mx = fmaxf(mx, logits[j]);
        float s = 0.f, e[5];
        for (int j = 0; j < 5; ++j) { e[j] = expf(logits[j] - mx); s += e[j]; }
        for (int j = 0; j < 5; ++j) out[b * 5 + j] = e[j] / s;
    }
}

extern "C" void kernel_launch(void* const* d_in, const int* in_sizes, int n_in,
                              void* d_out, int out_size, void* d_ws, size_t ws_size,
                              hipStream_t stream)
{
    const int B = 32, T = 32, L = 128;
    const int F1 = 64, F2 = 128, F3 = 256;

    const float* x   = (const float*)d_in[0];
    const float* Wx1 = (const float*)d_in[1];
    const float* Wh1 = (const float*)d_in[2];
    const float* b1  = (const float*)d_in[3];
    const float* Wx2 = (const float*)d_in[4];
    const float* Wh2 = (const float*)d_in[5];
    const float* b2  = (const float*)d_in[6];
    const float* Wx3 = (const float*)d_in[7];
    const float* Wh3 = (const float*)d_in[8];
    const float* b3  = (const float*)d_in[9];
    const float* g1  = (const float*)d_in[10];
    const float* be1 = (const float*)d_in[11];
    const float* m1  = (const float*)d_in[12];
    const float* v1  = (const float*)d_in[13];
    const float* g2  = (const float*)d_in[14];
    const float* be2 = (const float*)d_in[15];
    const float* m2  = (const float*)d_in[16];
    const float* v2  = (const float*)d_in[17];
    const float* g3  = (const float*)d_in[18];
    const float* be3 = (const float*)d_in[19];
    const float* m3  = (const float*)d_in[20];
    const float* v3  = (const float*)d_in[21];
    const float* D1  = (const float*)d_in[22];
    const float* db1 = (const float*)d_in[23];
    const float* D2  = (const float*)d_in[24];
    const float* db2 = (const float*)d_in[25];
    const float* D3  = (const float*)d_in[26];
    const float* db3 = (const float*)d_in[27];
    (void)in_sizes; (void)n_in; (void)out_size; (void)ws_size;

    // ---- workspace layout ----
    char* p = (char*)d_ws;
    ushort* h1seq = (ushort*)p; p += (size_t)B * T * L * F1 * 2;       // 16.8 MB
    ushort* h2seq = (ushort*)p; p += (size_t)B * T * L * F2 * 2;       // 33.6 MB
    ushort* h1a = (ushort*)p; p += (size_t)B * L * F1 * 2;
    ushort* h1b = (ushort*)p; p += (size_t)B * L * F1 * 2;
    ushort* h2a = (ushort*)p; p += (size_t)B * L * F2 * 2;
    ushort* h2b = (ushort*)p; p += (size_t)B * L * F2 * 2;
    ushort* h3a = (ushort*)p; p += (size_t)B * L * F3 * 2;
    ushort* h3b = (ushort*)p; p += (size_t)B * L * F3 * 2;
    float*  c1s = (float*)p; p += (size_t)B * L * F1 * 4;
    float*  c2s = (float*)p; p += (size_t)B * L * F2 * 4;
    float*  c3s = (float*)p; p += (size_t)B * L * F3 * 4;
    float*  h3bn = (float*)p; p += (size_t)B * L * F3 * 4;
    uint4*  wp1 = (uint4*)p; p += (size_t)2 * 7 * 512 * 16;
    uint4*  wp2 = (uint4*)p; p += (size_t)4 * 18 * 512 * 16;
    uint4*  wp3 = (uint4*)p; p += (size_t)8 * 36 * 512 * 16;
    float*  a1 = (float*)p; p += (size_t)B * 1024 * 4;
    float*  a2 = (float*)p; p += (size_t)B * 512 * 4;
    // partials: 256*32*1024*4 = 33.55 MB == h2seq slab size, dead by then
    float* partials = (float*)h2seq;

    // ---- pack weights ----
    pack_w<<<dim3(2, 7), 256, 0, stream>>>(Wx1, 1, Wh1, F1, wp1, 1, 7);
    pack_w<<<dim3(4, 18), 256, 0, stream>>>(Wx2, F1, Wh2, F2, wp2, 6, 18);
    pack_w<<<dim3(8, 36), 256, 0, stream>>>(Wx3, F2, Wh3, F3, wp3, 12, 36);

    // ---- zero initial states ----
    hipMemsetAsync(h1a, 0, (size_t)B * L * F1 * 2, stream);
    hipMemsetAsync(h2a, 0, (size_t)B * L * F2 * 2, stream);
    hipMemsetAsync(h3a, 0, (size_t)B * L * F3 * 2, stream);
    hipMemsetAsync(c1s, 0, (size_t)B * L * F1 * 4, stream);
    hipMemsetAsync(c2s, 0, (size_t)B * L * F2 * 4, stream);
    hipMemsetAsync(c3s, 0, (size_t)B * L * F3 * 4, stream);

    // ---- diagonal schedule: dispatch d runs L1@d, L2@d-1, L3@d-2 ----
    for (int d = 0; d < T + 2; ++d) {
        GateCfg c1c = {}, c2c = {}, c3c = {};

        int t1 = d;
        if (t1 >= 0 && t1 < T) {
            c1c.active = 1; c1c.cin1 = 1; c1c.bnf32 = 0;
            c1c.a0 = x + (long)t1 * L; c1c.a0_bs = (long)T * L;
            c1c.C0A = 32; c1c.S0 = 1; c1c.S = 7; c1c.F = F1; c1c.nf_log2 = 1;
            c1c.h_old = (t1 & 1) ? h1b : h1a;
            c1c.h_new = (t1 & 1) ? h1a : h1b;
            c1c.wp = wp1; c1c.bias = b1; c1c.c_state = c1s;
            c1c.bn_out = h1seq + (long)t1 * L * F1; c1c.bn_bs = (long)T * L * F1;
            c1c.bn_g = g1; c1c.bn_b = be1; c1c.bn_m = m1; c1c.bn_v = v1;
        }
        int t2 = d - 1;
        if (t2 >= 0 && t2 < T) {
            c2c.active = 1; c2c.cin1 = 0; c2c.bnf32 = 0;
            c2c.a0 = h1seq + (long)t2 * L * F1; c2c.a0_bs = (long)T * L * F1;
            c2c.C0A = F1; c2c.S0 = 6; c2c.S = 18; c2c.F = F2; c2c.nf_log2 = 2;
            c2c.h_old = (t2 & 1) ? h2b : h2a;
            c2c.h_new = (t2 & 1) ? h2a : h2b;
            c2c.wp = wp2; c2c.bias = b2; c2c.c_state = c2s;
            c2c.bn_out = h2seq + (long)t2 * L * F2; c2c.bn_bs = (long)T * L * F2;
            c2c.bn_g = g2; c2c.bn_b = be2; c2c.bn_m = m2; c2c.bn_v = v2;
        }
        int t3 = d - 2;
        if (t3 >= 0 && t3 < T) {
            c3c.active = 1; c3c.cin1 = 0; c3c.bnf32 = 1;
            c3c.a0 = h2seq + (long)t3 * L * F2; c3c.a0_bs = (long)T * L * F2;
            c3c.C0A = F2; c3c.S0 = 12; c3c.S = 36; c3c.F = F3; c3c.nf_log2 = 3;
            c3c.h_old = (t3 & 1) ? h3b : h3a;
            c3c.h_new = (t3 & 1) ? h3a : h3b;
            c3c.wp = wp3; c3c.bias = b3; c3c.c_state = c3s;
            c3c.bn_out = (t3 == T - 1) ? (void*)h3bn : nullptr;
            c3c.bn_bs = (long)L * F3;
            c3c.bn_g = g3; c3c.bn_b = be3; c3c.bn_m = m3; c3c.bn_v = v3;
        }
        gate_diag<<<896, 256, 0, stream>>>(c3c, c2c, c1c, L);
    }

    // ---- dense head ----
    {
        const int K = L * F3;              // 32768
        dense_partial<<<dim3(4, 256), 256, 0, stream>>>(h3bn, D1, partials, K, 1024);
        dense_reduce_relu<<<(B * 1024) / 256, 256, 0, stream>>>(partials, db1, a1, 1024, 256);
    }
    dense_relu<<<dim3(512 / 256, B), 256, 0, stream>>>(a1, D2, db2, a2, 1024, 512);
    dense_softmax<<<B, 64, 0, stream>>>(a2, D3, db3, (float*)d_out);
}